// Round 10
// baseline (254.222 us; speedup 1.0000x reference)
//
#include <hip/hip_runtime.h>

// Collapse: out = ((P3@M.T + 16c)@M.T + 4c)@M.T + c,  M = Wzf@Wsum.
//   M2 = M@M = NT(M, MT) ; Y1 = NT(P3,M)+16c ; u[j] = 4*dot(M[j,:],c0)+c0[j]
//   out = NT(Y1, M2) + u ; P3[t] = sum of tree t's 64 leaves.
// 3 dispatches:
//   D1 (2688): [0,256) M (VALU) | [256,512) MT (VALU) | [512,2560) pool | c0
//   D2 (320):  [0,128) Y1 | [128,192) M2 | [192,320) u
//   D3 (128):  out
// MFMA GEMMs: 16x16x32 bf16, exact 2-term split A*B ~= Ah*Bh + Ah*Bl + Al*Bh.
// M/MT as fp32 VALU GEMMs fused in D1: they use the VALU pipes the HBM-bound
// pool waves leave idle; small LDS/VGPR so pool keeps 32 waves/CU (R6 lesson).

#define HD 512

typedef __attribute__((ext_vector_type(8))) short bf16x8;
typedef __attribute__((ext_vector_type(4))) float f32x4;

struct __align__(16) MfmaSmem {        // 20480 B
    unsigned short Ah[64][40];
    unsigned short Al[64][40];
    unsigned short Bh[64][40];
    unsigned short Bl[64][40];
};

__device__ __forceinline__ void split8(const float4& v0, const float4& v1,
                                       bf16x8& hv, bf16x8& lv) {
    float f[8] = {v0.x, v0.y, v0.z, v0.w, v1.x, v1.y, v1.z, v1.w};
    #pragma unroll
    for (int i = 0; i < 8; ++i) {
        unsigned u = __float_as_uint(f[i]);
        hv[i] = (short)(u >> 16);
        float hi = __uint_as_float(u & 0xFFFF0000u);
        lv[i] = (short)(__float_as_uint(f[i] - hi) >> 16);
    }
}

// ---- MFMA NT GEMM: C[i0:+64, j0:+64] = A[64x512] @ Bt[64x512].T (+ bias) ----
template<bool BIAS>
__device__ __forceinline__
void mfma_gemm(const float* __restrict__ A, const float* __restrict__ Bt,
               float* __restrict__ C, const float* __restrict__ bias,
               float bscale, int i0, int j0, MfmaSmem& sm) {
    const int t = threadIdx.x;
    const int sr = t >> 2, sk = (t & 3) << 3;
    const int lane = t & 63, w = t >> 6;
    const int fm = lane & 15, fq = (lane >> 4) << 3;

    const float* ap = &A[(size_t)(i0 + sr) * HD + sk];
    const float* bp = &Bt[(size_t)(j0 + sr) * HD + sk];
    float4 a0 = *(const float4*)ap, a1 = *(const float4*)(ap + 4);
    float4 b0 = *(const float4*)bp, b1 = *(const float4*)(bp + 4);

    f32x4 acc[4] = {};

    for (int it = 0; it < 16; ++it) {
        __syncthreads();
        bf16x8 hv, lv;
        split8(a0, a1, hv, lv);
        *(bf16x8*)&sm.Ah[sr][sk] = hv;
        *(bf16x8*)&sm.Al[sr][sk] = lv;
        split8(b0, b1, hv, lv);
        *(bf16x8*)&sm.Bh[sr][sk] = hv;
        *(bf16x8*)&sm.Bl[sr][sk] = lv;
        __syncthreads();

        if (it < 15) {                    // prefetch next k-tile under MFMA
            const int k0n = (it + 1) << 5;
            a0 = *(const float4*)(ap + k0n);
            a1 = *(const float4*)(ap + k0n + 4);
            b0 = *(const float4*)(bp + k0n);
            b1 = *(const float4*)(bp + k0n + 4);
        }

        bf16x8 ah = *(const bf16x8*)&sm.Ah[(w << 4) + fm][fq];
        bf16x8 al = *(const bf16x8*)&sm.Al[(w << 4) + fm][fq];
        #pragma unroll
        for (int ct = 0; ct < 4; ++ct) {
            bf16x8 bh = *(const bf16x8*)&sm.Bh[(ct << 4) + fm][fq];
            bf16x8 bl = *(const bf16x8*)&sm.Bl[(ct << 4) + fm][fq];
            acc[ct] = __builtin_amdgcn_mfma_f32_16x16x32_bf16(ah, bh, acc[ct], 0, 0, 0);
            acc[ct] = __builtin_amdgcn_mfma_f32_16x16x32_bf16(ah, bl, acc[ct], 0, 0, 0);
            acc[ct] = __builtin_amdgcn_mfma_f32_16x16x32_bf16(al, bh, acc[ct], 0, 0, 0);
        }
    }

    const int orow = i0 + (w << 4) + ((lane >> 4) << 2);
    #pragma unroll
    for (int ct = 0; ct < 4; ++ct) {
        const int col = j0 + (ct << 4) + fm;
        float bv = BIAS ? bscale * bias[col] : 0.f;
        #pragma unroll
        for (int r = 0; r < 4; ++r)
            C[(size_t)(orow + r) * HD + col] = acc[ct][r] + bv;
    }
}

// ---- small VALU GEMM for M / MT (32x32 tile, KT=16, 4224 B LDS) ----
// MODE 0 (M = Wzf@Wsum):  As[kk][i] = Wzf[i0+i][k0+kk]           (row scatter)
//                         Bs[kk][j] = sum_q Wz[q][k0+kk][j0+j]   (direct rows)
//   -> C[i][j] = sum_k Wzf[i][k] Wsum[k][j] = M[i0+i][j0+j]
// MODE 1 (MT):            As[kk][i] = sum_q Wz[q][k0+kk][i0+i]   (direct rows)
//                         Bs[kk][j] = Wzf[j0+j][k0+kk]           (row scatter)
//   -> C[i][j] = sum_k Wsum[k][i] Wzf[j][k] = M[j0+j][i0+i] = MT[i0+i][j0+j]
struct VSmem { float As[16][33]; float Bs[16][33]; };

template<int MODE>
__device__ __forceinline__
void vgemm(const float* __restrict__ Wzf, const float* __restrict__ Wz,
           float* __restrict__ C, int i0, int j0, VSmem& sm) {
    const int t = threadIdx.x;
    const int ti = t >> 4, tj = t & 15;
    float a00 = 0.f, a01 = 0.f, a10 = 0.f, a11 = 0.f;

    for (int k0 = 0; k0 < HD; k0 += 16) {
        __syncthreads();
        {   // scatter staging from Wzf rows
            const int r = t >> 3, kp = (t & 7) << 1;
            const int row = (MODE == 0) ? i0 + r : j0 + r;
            float2 v = *(const float2*)&Wzf[(size_t)row * HD + k0 + kp];
            if (MODE == 0) { sm.As[kp][r] = v.x; sm.As[kp + 1][r] = v.y; }
            else           { sm.Bs[kp][r] = v.x; sm.Bs[kp + 1][r] = v.y; }
        }
        {   // direct 4-slice staging from Wz rows
            const int kk = t >> 4, j2 = (t & 15) << 1;
            const int col = (MODE == 0) ? j0 + j2 : i0 + j2;
            const float* src = &Wz[(size_t)(k0 + kk) * HD + col];
            float sx = 0.f, sy = 0.f;
            #pragma unroll
            for (int q = 0; q < 4; ++q) {
                float2 v = *(const float2*)(src + q * 262144);
                sx += v.x; sy += v.y;
            }
            if (MODE == 0) { sm.Bs[kk][j2] = sx; sm.Bs[kk][j2 + 1] = sy; }
            else           { sm.As[kk][j2] = sx; sm.As[kk][j2 + 1] = sy; }
        }
        __syncthreads();
        #pragma unroll
        for (int kk = 0; kk < 16; ++kk) {
            float x0 = sm.As[kk][2 * ti], x1 = sm.As[kk][2 * ti + 1];
            float y0 = sm.Bs[kk][2 * tj], y1 = sm.Bs[kk][2 * tj + 1];
            a00 = fmaf(x0, y0, a00); a01 = fmaf(x0, y1, a01);
            a10 = fmaf(x1, y0, a10); a11 = fmaf(x1, y1, a11);
        }
    }
    float* c0p = &C[(size_t)(i0 + 2 * ti) * HD + j0 + 2 * tj];
    c0p[0] = a00; c0p[1] = a01;
    c0p[HD] = a10; c0p[HD + 1] = a11;
}

// ---- D1: [0,256) M | [256,512) MT | [512,2560) pool | [2560,2688) c0 ----
union D1Smem { VSmem v; float4 red[192]; };

__global__ __launch_bounds__(256) void kD1(
        const float* __restrict__ x, const float* __restrict__ Wz,
        const float* __restrict__ bz, const float* __restrict__ Wzf,
        const float* __restrict__ bzf,
        float* __restrict__ P3, float* __restrict__ M, float* __restrict__ MT,
        float* __restrict__ c0) {
    __shared__ D1Smem sm;
    const int b = blockIdx.x, t = threadIdx.x;
    if (b < 256) {
        vgemm<0>(Wzf, Wz, M, (b >> 4) << 5, (b & 15) << 5, sm.v);
    } else if (b < 512) {
        const int bb = b - 256;
        vgemm<1>(Wzf, Wz, MT, (bb >> 4) << 5, (bb & 15) << 5, sm.v);
    } else if (b < 2560) {
        // pool-direct: block = (tree, col-half); wave = row quarter
        const int pb = b - 512, tree = pb >> 1, cbase = (pb & 1) << 6;
        const int c = t & 63, sub = t >> 6;
        const float4* xp = (const float4*)x + (size_t)tree * 8192
                         + (sub << 4) * 128 + cbase + c;
        float4 acc = make_float4(0.f, 0.f, 0.f, 0.f);
        #pragma unroll
        for (int g = 0; g < 2; ++g) {
            float4 v[8];
            #pragma unroll
            for (int i = 0; i < 8; ++i) v[i] = xp[(size_t)(g * 8 + i) * 128];
            #pragma unroll
            for (int i = 0; i < 8; ++i) {
                acc.x += v[i].x; acc.y += v[i].y; acc.z += v[i].z; acc.w += v[i].w;
            }
        }
        if (sub) sm.red[((sub - 1) << 6) + c] = acc;
        __syncthreads();
        if (!sub) {
            float4 r0 = sm.red[c], r1 = sm.red[64 + c], r2 = sm.red[128 + c];
            acc.x += (r0.x + r1.x) + r2.x;
            acc.y += (r0.y + r1.y) + r2.y;
            acc.z += (r0.z + r1.z) + r2.z;
            acc.w += (r0.w + r1.w) + r2.w;
            ((float4*)P3)[tree * 128 + cbase + c] = acc;
        }
    } else {
        // c0[j] = 4*(dot(bsum, Wzf[j,:]) + bzf[j]); one j per wave
        const int lane = t & 63, w = t >> 6, hb = lane << 3;
        const int j = (b - 2560) * 4 + w;
        float4 s0 = *(const float4*)&bz[hb];
        float4 s1 = *(const float4*)&bz[hb + 4];
        #pragma unroll
        for (int q = 1; q < 4; ++q) {
            float4 t0 = *(const float4*)&bz[q * HD + hb];
            float4 t1 = *(const float4*)&bz[q * HD + hb + 4];
            s0.x += t0.x; s0.y += t0.y; s0.z += t0.z; s0.w += t0.w;
            s1.x += t1.x; s1.y += t1.y; s1.z += t1.z; s1.w += t1.w;
        }
        const float4* wr = (const float4*)&Wzf[(size_t)j * HD + hb];
        float4 w0 = wr[0], w1 = wr[1];
        float p = w0.x * s0.x + w0.y * s0.y + w0.z * s0.z + w0.w * s0.w
                + w1.x * s1.x + w1.y * s1.y + w1.z * s1.z + w1.w * s1.w;
        #pragma unroll
        for (int off = 32; off > 0; off >>= 1) p += __shfl_down(p, off);
        if (lane == 0) c0[j] = 4.f * (p + bzf[j]);
    }
}

// ---- D2: [0,128) Y1 = NT(P3,M)+16c | [128,192) M2 = NT(M,MT) | [192,320) u ----
__global__ __launch_bounds__(256) void kD2(
        const float* __restrict__ P3, const float* __restrict__ M,
        const float* __restrict__ MT, const float* __restrict__ c0,
        float* __restrict__ Y1, float* __restrict__ M2, float* __restrict__ u) {
    __shared__ MfmaSmem sm;
    const int b = blockIdx.x, t = threadIdx.x;
    if (b < 128) {
        mfma_gemm<true>(P3, M, Y1, c0, 16.f, (b >> 3) << 6, (b & 7) << 6, sm);
    } else if (b < 192) {
        const int bb = b - 128;
        mfma_gemm<false>(M, MT, M2, nullptr, 0.f,
                         (bb >> 3) << 6, (bb & 7) << 6, sm);
    } else {
        const int lane = t & 63, w = t >> 6, hb = lane << 3;
        const int j = (b - 192) * 4 + w;
        const float4* mr = (const float4*)&M[(size_t)j * HD + hb];
        const float4* cr = (const float4*)&c0[hb];
        float4 m0 = mr[0], m1 = mr[1], q0 = cr[0], q1 = cr[1];
        float p = m0.x * q0.x + m0.y * q0.y + m0.z * q0.z + m0.w * q0.w
                + m1.x * q1.x + m1.y * q1.y + m1.z * q1.z + m1.w * q1.w;
        #pragma unroll
        for (int off = 32; off > 0; off >>= 1) p += __shfl_down(p, off);
        if (lane == 0) u[j] = 4.f * p + c0[j];
    }
}

// ---- D3: out = NT(Y1, M2) + u ----
__global__ __launch_bounds__(256) void kD3(
        const float* __restrict__ Y1, const float* __restrict__ M2,
        const float* __restrict__ u, float* __restrict__ out) {
    __shared__ MfmaSmem sm;
    const int b = blockIdx.x;
    mfma_gemm<true>(Y1, M2, out, u, 1.f, (b >> 3) << 6, (b & 7) << 6, sm);
}

extern "C" void kernel_launch(void* const* d_in, const int* in_sizes, int n_in,
                              void* d_out, int out_size, void* d_ws, size_t ws_size,
                              hipStream_t stream) {
    const float* x   = (const float*)d_in[0];
    const float* Wz  = (const float*)d_in[1];
    const float* bz  = (const float*)d_in[2];
    const float* Wzf = (const float*)d_in[3];
    const float* bzf = (const float*)d_in[4];
    float* out = (float*)d_out;

    float* ws = (float*)d_ws;
    float* P3 = ws;                 // 1024*512
    float* Y1 = ws + 524288;        // 1024*512
    float* M  = ws + 1048576;       // 512*512
    float* MT = ws + 1310720;       // 512*512
    float* M2 = ws + 1572864;       // 512*512
    float* c0 = ws + 1835008;       // 512
    float* u  = ws + 1835520;       // 512

    hipLaunchKernelGGL(kD1, dim3(2688), dim3(256), 0, stream,
                       x, Wz, bz, Wzf, bzf, P3, M, MT, c0);
    hipLaunchKernelGGL(kD2, dim3(320), dim3(256), 0, stream,
                       P3, M, MT, c0, Y1, M2, u);
    hipLaunchKernelGGL(kD3, dim3(128), dim3(256), 0, stream, Y1, M2, u, out);
}